// Round 6
// baseline (411.344 us; speedup 1.0000x reference)
//
#include <hip/hip_runtime.h>
#include <stdint.h>

typedef unsigned short u16;
typedef __bf16 bfrag __attribute__((ext_vector_type(8)));   // 8 bf16 = 4 VGPRs (MFMA A/B, K=32)
typedef short sh4 __attribute__((ext_vector_type(4)));      // 4 bf16 = 2 VGPRs (MFMA A/B, K=16)
typedef short sh8 __attribute__((ext_vector_type(8)));
typedef float f32x4 __attribute__((ext_vector_type(4)));    // MFMA C/D

#define LOG2E 1.44269504088896340736f

__device__ __forceinline__ u16 f2bf(float f) {
    unsigned u = __builtin_bit_cast(unsigned, f);
    u = (u + 0x7fffu + ((u >> 16) & 1u)) >> 16;
    return (u16)u;
}
__device__ __forceinline__ float bf2f(u16 x) {
    unsigned u = ((unsigned)x) << 16;
    return __builtin_bit_cast(float, u);
}

__device__ __forceinline__ void gl_lds16(const u16* g, u16* l) {
#if __has_builtin(__builtin_amdgcn_global_load_lds)
    __builtin_amdgcn_global_load_lds(
        (const __attribute__((address_space(1))) unsigned int*)g,
        (__attribute__((address_space(3))) unsigned int*)l, 16, 0, 0);
#else
    *(uint4*)l = *(const uint4*)g;
#endif
}

// PV micro-op: O^T[16d][16q] += V^T-frag (A) * P^T-frag (B), K=16
__device__ __forceinline__ f32x4 pv_mfma(sh4 v, sh4 p, f32x4 c) {
#if __has_builtin(__builtin_amdgcn_mfma_f32_16x16x16bf16_1k)
    return __builtin_amdgcn_mfma_f32_16x16x16bf16_1k(v, p, c, 0, 0, 0);
#else
    sh8 a = {v.x, v.y, v.z, v.w, 0, 0, 0, 0};
    sh8 b = {p.x, p.y, p.z, p.w, 0, 0, 0, 0};
    return __builtin_amdgcn_mfma_f32_16x16x32_bf16(
        __builtin_bit_cast(bfrag, a), __builtin_bit_cast(bfrag, b), c, 0, 0, 0);
#endif
}

__device__ __forceinline__ sh4 pack4(const f32x4& v) {
    sh4 r;
    r.x = (short)f2bf(v[0]); r.y = (short)f2bf(v[1]);
    r.z = (short)f2bf(v[2]); r.w = (short)f2bf(v[3]);
    return r;
}

// ---------------- fp32 -> bf16 elementwise ----------------
__global__ __launch_bounds__(256) void cvt_f32_bf16(const float* __restrict__ s,
                                                    u16* __restrict__ d, int n4) {
    int i = blockIdx.x * 256 + threadIdx.x;
    if (i < n4) {
        float4 v = ((const float4*)s)[i];
        uint2 o;
        o.x = (unsigned)f2bf(v.x) | ((unsigned)f2bf(v.y) << 16);
        o.y = (unsigned)f2bf(v.z) | ((unsigned)f2bf(v.w) << 16);
        ((uint2*)d)[i] = o;
    }
}

// ---------------- transpose + convert ----------------
__global__ __launch_bounds__(256) void transpose_cvt(const float* __restrict__ src,
                                                     u16* __restrict__ dst,
                                                     int rows, int cols) {
    __shared__ float tile[32][33];
    int c0 = blockIdx.x * 32, r0 = blockIdx.y * 32;
    int tx = threadIdx.x, ty = threadIdx.y;
#pragma unroll
    for (int i = 0; i < 32; i += 8)
        tile[ty + i][tx] = src[(size_t)(r0 + ty + i) * cols + c0 + tx];
    __syncthreads();
#pragma unroll
    for (int i = 0; i < 32; i += 8)
        dst[(size_t)(c0 + ty + i) * rows + r0 + tx] = f2bf(tile[tx][ty + i]);
}

// ---------------- GEMM: C[M][N] = A[M][K] * B[N][K]^T, XOR-swizzled LDS ----------------
template <typename OutT>
__global__ __launch_bounds__(256) void gemm_bt(const u16* __restrict__ A,
                                               const u16* __restrict__ B,
                                               OutT* __restrict__ C,
                                               int K, int ldc) {
    __shared__ u16 As[128 * 32];
    __shared__ u16 Bs[128 * 32];
    const int tid = threadIdx.x;
    const int wave = tid >> 6, lane = tid & 63;
    const int quad = lane >> 4, l16 = lane & 15;
    const int bm = blockIdx.x * 128, bn = blockIdx.y * 128;
    const int wm = (wave & 1) * 64, wn = (wave >> 1) * 64;

    f32x4 acc[4][4] = {};

    const int srow = tid >> 2;
    const int sch = (tid & 3) ^ ((tid >> 4) & 3);
    const u16* aPtr = A + (size_t)(bm + srow) * K + sch * 8;
    const u16* bPtr = B + (size_t)(bn + srow) * K + sch * 8;
    const int rsw = quad ^ ((l16 >> 2) & 3);

    for (int kb = 0; kb < K; kb += 32) {
        __syncthreads();
#pragma unroll
        for (int p = 0; p < 2; ++p) {
            gl_lds16(aPtr + (size_t)p * 64 * K, &As[(p * 256 + tid) * 8]);
            gl_lds16(bPtr + (size_t)p * 64 * K, &Bs[(p * 256 + tid) * 8]);
        }
        __syncthreads();
        bfrag af[4], bfr[4];
#pragma unroll
        for (int mi = 0; mi < 4; ++mi)
            af[mi] = *(const bfrag*)&As[((wm + mi * 16 + l16) * 4 + rsw) * 8];
#pragma unroll
        for (int ni = 0; ni < 4; ++ni)
            bfr[ni] = *(const bfrag*)&Bs[((wn + ni * 16 + l16) * 4 + rsw) * 8];
#pragma unroll
        for (int mi = 0; mi < 4; ++mi)
#pragma unroll
            for (int ni = 0; ni < 4; ++ni)
                acc[mi][ni] = __builtin_amdgcn_mfma_f32_16x16x32_bf16(af[mi], bfr[ni], acc[mi][ni], 0, 0, 0);
        aPtr += 32;
        bPtr += 32;
    }
#pragma unroll
    for (int mi = 0; mi < 4; ++mi)
#pragma unroll
        for (int ni = 0; ni < 4; ++ni)
#pragma unroll
            for (int r = 0; r < 4; ++r) {
                int row = bm + wm + mi * 16 + quad * 4 + r;
                int col = bn + wn + ni * 16 + l16;
                float v = acc[mi][ni][r];
                if constexpr (sizeof(OutT) == 2)
                    C[(size_t)row * ldc + col] = f2bf(v);
                else
                    C[(size_t)row * ldc + col] = v;
            }
}

// ---------------- RMSNorm + RoPE (q prescaled by softmax scale * log2e) ----------------
__global__ __launch_bounds__(256) void rmsrope(u16* __restrict__ qkv,
                                               const float* __restrict__ cosb,
                                               const float* __restrict__ sinb,
                                               const float* __restrict__ qw,
                                               const float* __restrict__ kw) {
    const float c1 = 0.08838834764831845f * LOG2E;
    int wave = threadIdx.x >> 6, lane = threadIdx.x & 63;
    int pi = blockIdx.x * 4 + wave;
    int m = pi / 20, hsel = pi % 20;
    int col0 = hsel < 16 ? hsel * 128 : 2048 + (hsel - 16) * 128;
    const float* w = hsel < 16 ? qw : kw;
    float sc = hsel < 16 ? c1 : 1.0f;
    int s = m & 2047;
    u16* p = qkv + (size_t)m * 3072 + col0;
    float x1 = bf2f(p[lane]), x2 = bf2f(p[lane + 64]);
    float ss = x1 * x1 + x2 * x2;
#pragma unroll
    for (int off = 32; off; off >>= 1) ss += __shfl_xor(ss, off, 64);
    float inv = rsqrtf(ss * (1.0f / 128.0f) + 1e-6f);
    float y1 = x1 * inv * w[lane], y2 = x2 * inv * w[lane + 64];
    const float* cp = cosb + (size_t)s * 128;
    const float* sp = sinb + (size_t)s * 128;
    float o1 = y1 * cp[lane] - y2 * sp[lane];
    float o2 = y2 * cp[lane + 64] + y1 * sp[lane + 64];
    p[lane] = f2bf(o1 * sc);
    p[lane + 64] = f2bf(o2 * sc);
}

// ---------------- V transpose ----------------
__global__ __launch_bounds__(256) void transpose_v(const u16* __restrict__ qkv,
                                                   u16* __restrict__ vT) {
    __shared__ u16 t[32][33];
    int bh = blockIdx.z, b = bh >> 2, kvh = bh & 3;
    int s0 = blockIdx.y * 32, d0 = blockIdx.x * 32;
    int tx = threadIdx.x, ty = threadIdx.y;
    const u16* src = qkv + (size_t)(b * 2048) * 3072 + 2560 + kvh * 128;
#pragma unroll
    for (int i = 0; i < 32; i += 8)
        t[ty + i][tx] = src[(size_t)(s0 + ty + i) * 3072 + d0 + tx];
    __syncthreads();
    u16* dst = vT + (size_t)bh * 128 * 2048;
#pragma unroll
    for (int i = 0; i < 32; i += 8)
        dst[(size_t)(d0 + ty + i) * 2048 + s0 + tx] = t[tx][ty + i];
}

// ---------------- causal flash attention: split-KV + in-block combine ----------------
// grid (32 bh, 32 qt), block 256 (4 waves). qt = 31-by (heavy blocks dispatch first, LPT).
// Wave-pair A (waves 0,1): kv [0, 32(qt+1)); pair B (waves 2,3): kv [32(qt+1), 64(qt+1)).
// Within a pair, wave w2 owns q rows [qt*64+w2*32, +32) as 2 subtiles of 16 (S^T form).
// No-max softmax (q prescaled by scale*log2e) => partials combine as O_A+O_B, l_A+l_B.
// LDS map (bytes): [0,8K) p0-K | [8K,16K) p0-V | [16K,24K) p1-K | [24K,32K) p1-V | [32K,33K) l-exch.
// Combine reuses [0,32K) for the O exchange (after barrier).
__global__ __launch_bounds__(256) void attn_kernel(const u16* __restrict__ qkv,
                                                   const u16* __restrict__ vT,
                                                   u16* __restrict__ out) {
    __shared__ __align__(16) u16 smem[16896];  // 33792 B
    const int tid = threadIdx.x, wave = tid >> 6, lane = tid & 63;
    const int quad = lane >> 4, l16 = lane & 15;
    const int pairB = wave >> 1, w2 = wave & 1, pt = tid & 127;
    const int bh = blockIdx.x, b = bh >> 4, h = bh & 15, kvh = h >> 2;
    const int qt = 31 - blockIdx.y;
    const size_t rowBase = (size_t)b * 2048;
    const int kcol0 = 2048 + kvh * 128;
    const u16* vTbase = vT + (size_t)(b * 4 + kvh) * 128 * 2048;

    u16* KsP  = smem + pairB * 8192;            // [32 kv][16 chunks ^ (kv&15)] of 8 u16
    u16* VsP  = smem + 4096 + pairB * 8192;     // [128 d][4 chunks ^ ((d>>2)&3)] of 8 u16
    const int q0 = qt * 64 + w2 * 32;           // wave's first q row
    const int qmax = q0 + 31;                   // wave's last q row
    const int kvbase = pairB * 32 * (qt + 1);   // this pair's kv start

    // Q B-frags (K=32) for 2 q-subtiles
    bfrag qf[2][4];
#pragma unroll
    for (int t2 = 0; t2 < 2; ++t2) {
        const u16* qp = qkv + (rowBase + q0 + t2 * 16 + l16) * 3072 + h * 128 + quad * 8;
#pragma unroll
        for (int ks = 0; ks < 4; ++ks) qf[t2][ks] = *(const bfrag*)(qp + ks * 32);
    }

    f32x4 o[2][8] = {};
    float lrun[2] = {0.f, 0.f};

    for (int it = 0; it <= qt; ++it) {
        const int kv0 = kvbase + it * 32;
        __syncthreads();
        // stage this pair's K tile: 32 rows x 16 chunks = 512, by 128 threads
#pragma unroll
        for (int i = 0; i < 4; ++i) {
            int c = i * 128 + pt, kv = c >> 4, ch = c & 15;
            gl_lds16(qkv + (rowBase + kv0 + kv) * 3072 + kcol0 + (ch ^ (kv & 15)) * 8,
                     &KsP[c * 8]);
        }
        // stage this pair's V^T tile: 128 rows x 4 chunks = 512
#pragma unroll
        for (int i = 0; i < 4; ++i) {
            int c = i * 128 + pt, d = c >> 2, ch = c & 3;
            gl_lds16(vTbase + (size_t)d * 2048 + kv0 + (ch ^ ((d >> 2) & 3)) * 8, &VsP[c * 8]);
        }
        __syncthreads();

        if (kv0 > qmax) continue;  // fully-masked tile for this wave (barriers already done)

        // S^T = K * Q^T : 2 kv-subtiles (m) x 2 q-subtiles (t2)
        f32x4 sa[2][2] = {};
#pragma unroll
        for (int ks = 0; ks < 4; ++ks)
#pragma unroll
            for (int m = 0; m < 2; ++m) {
                bfrag kf = *(const bfrag*)&KsP[((m * 16 + l16) * 16 + ((ks * 4 + quad) ^ l16)) * 8];
#pragma unroll
                for (int t2 = 0; t2 < 2; ++t2)
                    sa[t2][m] = __builtin_amdgcn_mfma_f32_16x16x32_bf16(kf, qf[t2][ks], sa[t2][m], 0, 0, 0);
            }

        // no-max softmax
        sh4 pf[2][2];
#pragma unroll
        for (int t2 = 0; t2 < 2; ++t2) {
            const int qrow = q0 + t2 * 16 + l16;
            if (kv0 + 31 > q0 + t2 * 16) {  // tile overlaps diagonal: mask
#pragma unroll
                for (int m = 0; m < 2; ++m)
#pragma unroll
                    for (int r = 0; r < 4; ++r)
                        if (kv0 + m * 16 + quad * 4 + r > qrow) sa[t2][m][r] = -3e38f;
            }
            float rs = 0.f;
#pragma unroll
            for (int m = 0; m < 2; ++m)
#pragma unroll
                for (int r = 0; r < 4; ++r) {
                    float pe = exp2f(fminf(sa[t2][m][r], 60.f));
                    sa[t2][m][r] = pe;
                    rs += pe;
                }
            rs += __shfl_xor(rs, 16, 64);
            rs += __shfl_xor(rs, 32, 64);
            lrun[t2] += rs;
#pragma unroll
            for (int m = 0; m < 2; ++m) pf[t2][m] = pack4(sa[t2][m]);
        }

        // O^T += V^T * P^T
#pragma unroll
        for (int k2 = 0; k2 < 2; ++k2)
#pragma unroll
            for (int dt = 0; dt < 8; ++dt) {
                int d = dt * 16 + l16;
                sh4 vf = *(const sh4*)&VsP[(d * 4 + ((k2 * 2 + (quad >> 1)) ^ ((l16 >> 2) & 3))) * 8 +
                                           (quad & 1) * 4];
#pragma unroll
                for (int t2 = 0; t2 < 2; ++t2)
                    o[t2][dt] = pv_mfma(vf, pf[t2][k2], o[t2][dt]);
            }
    }

    // ---- combine pair B into pair A via LDS, then normalize + store ----
    __syncthreads();
    if (wave >= 2) {
        float* ob = (float*)smem + (wave - 2) * 4096;            // bytes [0,32K)
        float* lb = (float*)(smem + 16384) + (wave - 2) * 128;   // bytes [32K,33K)
#pragma unroll
        for (int t2 = 0; t2 < 2; ++t2) {
#pragma unroll
            for (int dt = 0; dt < 8; ++dt)
                *(f32x4*)(ob + (t2 * 8 + dt) * 256 + lane * 4) = o[t2][dt];
            lb[t2 * 64 + lane] = lrun[t2];
        }
    }
    __syncthreads();
    if (wave < 2) {
        float* ob = (float*)smem + wave * 4096;
        float* lb = (float*)(smem + 16384) + wave * 128;
#pragma unroll
        for (int t2 = 0; t2 < 2; ++t2) {
            float l2 = lrun[t2] + lb[t2 * 64 + lane];
            float inv = 1.0f / l2;
            size_t orow = (rowBase + q0 + t2 * 16 + l16) * 2048 + h * 128 + quad * 4;
#pragma unroll
            for (int dt = 0; dt < 8; ++dt) {
                f32x4 ov = o[t2][dt] + *(const f32x4*)(ob + (t2 * 8 + dt) * 256 + lane * 4);
                uint2 pk;
                pk.x = (unsigned)f2bf(ov[0] * inv) | ((unsigned)f2bf(ov[1] * inv) << 16);
                pk.y = (unsigned)f2bf(ov[2] * inv) | ((unsigned)f2bf(ov[3] * inv) << 16);
                *(uint2*)(out + orow + dt * 16) = pk;
            }
        }
    }
}

extern "C" void kernel_launch(void* const* d_in, const int* in_sizes, int n_in,
                              void* d_out, int out_size, void* d_ws, size_t ws_size,
                              hipStream_t stream) {
    const float* hs   = (const float*)d_in[0];
    const float* cosb = (const float*)d_in[1];
    const float* sinb = (const float*)d_in[2];
    const float* Wq = (const float*)d_in[4];
    const float* Wk = (const float*)d_in[5];
    const float* Wv = (const float*)d_in[6];
    const float* Wo = (const float*)d_in[7];
    const float* qw = (const float*)d_in[8];
    const float* kw = (const float*)d_in[9];
    float* out = (float*)d_out;

    char* ws = (char*)d_ws;
    u16* hsb   = (u16*)(ws + 0);          // 16 MB: hs bf16; later reused as attn-out bf16
    u16* wqkvT = (u16*)(ws + 16777216);   // 12 MB
    u16* woT   = (u16*)(ws + 29360128);   // 8 MB
    u16* qkv   = (u16*)(ws + 37748736);   // 24 MB
    u16* vT    = (u16*)(ws + 62914560);   // 4 MB

    dim3 tb(32, 8);
    cvt_f32_bf16<<<8192, 256, 0, stream>>>(hs, hsb, 2097152);
    transpose_cvt<<<dim3(64, 64), tb, 0, stream>>>(Wq, wqkvT, 2048, 2048);
    transpose_cvt<<<dim3(16, 64), tb, 0, stream>>>(Wk, wqkvT + (size_t)2048 * 2048, 2048, 512);
    transpose_cvt<<<dim3(16, 64), tb, 0, stream>>>(Wv, wqkvT + (size_t)2560 * 2048, 2048, 512);
    transpose_cvt<<<dim3(64, 64), tb, 0, stream>>>(Wo, woT, 2048, 2048);

    gemm_bt<u16><<<dim3(32, 24), 256, 0, stream>>>(hsb, wqkvT, qkv, 2048, 3072);

    rmsrope<<<20480, 256, 0, stream>>>(qkv, cosb, sinb, qw, kw);
    transpose_v<<<dim3(4, 64, 8), tb, 0, stream>>>(qkv, vT);

    attn_kernel<<<dim3(32, 32), 256, 0, stream>>>(qkv, vT, hsb);

    gemm_bt<float><<<dim3(32, 16), 256, 0, stream>>>(hsb, woT, out, 2048, 2048);
}

// Round 7
// 368.356 us; speedup vs baseline: 1.1167x; 1.1167x over previous
//
#include <hip/hip_runtime.h>
#include <stdint.h>

typedef unsigned short u16;
typedef __bf16 bfrag __attribute__((ext_vector_type(8)));   // 8 bf16 = 4 VGPRs (MFMA A/B, K=32)
typedef short sh4 __attribute__((ext_vector_type(4)));      // 4 bf16 = 2 VGPRs (MFMA A/B, K=16)
typedef short sh8 __attribute__((ext_vector_type(8)));
typedef float f32x4 __attribute__((ext_vector_type(4)));    // MFMA C/D

#define LOG2E 1.44269504088896340736f

__device__ __forceinline__ u16 f2bf(float f) {
    unsigned u = __builtin_bit_cast(unsigned, f);
    u = (u + 0x7fffu + ((u >> 16) & 1u)) >> 16;
    return (u16)u;
}
__device__ __forceinline__ float bf2f(u16 x) {
    unsigned u = ((unsigned)x) << 16;
    return __builtin_bit_cast(float, u);
}

__device__ __forceinline__ void gl_lds16(const u16* g, u16* l) {
#if __has_builtin(__builtin_amdgcn_global_load_lds)
    __builtin_amdgcn_global_load_lds(
        (const __attribute__((address_space(1))) unsigned int*)g,
        (__attribute__((address_space(3))) unsigned int*)l, 16, 0, 0);
#else
    *(uint4*)l = *(const uint4*)g;
#endif
}

// PV micro-op: O^T[16d][16q] += V^T-frag (A) * P^T-frag (B), K=16
__device__ __forceinline__ f32x4 pv_mfma(sh4 v, sh4 p, f32x4 c) {
#if __has_builtin(__builtin_amdgcn_mfma_f32_16x16x16bf16_1k)
    return __builtin_amdgcn_mfma_f32_16x16x16bf16_1k(v, p, c, 0, 0, 0);
#else
    sh8 a = {v.x, v.y, v.z, v.w, 0, 0, 0, 0};
    sh8 b = {p.x, p.y, p.z, p.w, 0, 0, 0, 0};
    return __builtin_amdgcn_mfma_f32_16x16x32_bf16(
        __builtin_bit_cast(bfrag, a), __builtin_bit_cast(bfrag, b), c, 0, 0, 0);
#endif
}

__device__ __forceinline__ sh4 pack4(const f32x4& v) {
    sh4 r;
    r.x = (short)f2bf(v[0]); r.y = (short)f2bf(v[1]);
    r.z = (short)f2bf(v[2]); r.w = (short)f2bf(v[3]);
    return r;
}

// ---------------- fp32 -> bf16 elementwise ----------------
__global__ __launch_bounds__(256) void cvt_f32_bf16(const float* __restrict__ s,
                                                    u16* __restrict__ d, int n4) {
    int i = blockIdx.x * 256 + threadIdx.x;
    if (i < n4) {
        float4 v = ((const float4*)s)[i];
        uint2 o;
        o.x = (unsigned)f2bf(v.x) | ((unsigned)f2bf(v.y) << 16);
        o.y = (unsigned)f2bf(v.z) | ((unsigned)f2bf(v.w) << 16);
        ((uint2*)d)[i] = o;
    }
}

// ---------------- transpose + convert ----------------
__global__ __launch_bounds__(256) void transpose_cvt(const float* __restrict__ src,
                                                     u16* __restrict__ dst,
                                                     int rows, int cols) {
    __shared__ float tile[32][33];
    int c0 = blockIdx.x * 32, r0 = blockIdx.y * 32;
    int tx = threadIdx.x, ty = threadIdx.y;
#pragma unroll
    for (int i = 0; i < 32; i += 8)
        tile[ty + i][tx] = src[(size_t)(r0 + ty + i) * cols + c0 + tx];
    __syncthreads();
#pragma unroll
    for (int i = 0; i < 32; i += 8)
        dst[(size_t)(c0 + ty + i) * rows + r0 + tx] = f2bf(tile[tx][ty + i]);
}

// ---------------- GEMM: C[M][N] = A[M][K] * B[N][K]^T, XOR-swizzled LDS ----------------
template <typename OutT>
__global__ __launch_bounds__(256) void gemm_bt(const u16* __restrict__ A,
                                               const u16* __restrict__ B,
                                               OutT* __restrict__ C,
                                               int K, int ldc) {
    __shared__ u16 As[128 * 32];
    __shared__ u16 Bs[128 * 32];
    const int tid = threadIdx.x;
    const int wave = tid >> 6, lane = tid & 63;
    const int quad = lane >> 4, l16 = lane & 15;
    const int bm = blockIdx.x * 128, bn = blockIdx.y * 128;
    const int wm = (wave & 1) * 64, wn = (wave >> 1) * 64;

    f32x4 acc[4][4] = {};

    const int srow = tid >> 2;
    const int sch = (tid & 3) ^ ((tid >> 4) & 3);
    const u16* aPtr = A + (size_t)(bm + srow) * K + sch * 8;
    const u16* bPtr = B + (size_t)(bn + srow) * K + sch * 8;
    const int rsw = quad ^ ((l16 >> 2) & 3);

    for (int kb = 0; kb < K; kb += 32) {
        __syncthreads();
#pragma unroll
        for (int p = 0; p < 2; ++p) {
            gl_lds16(aPtr + (size_t)p * 64 * K, &As[(p * 256 + tid) * 8]);
            gl_lds16(bPtr + (size_t)p * 64 * K, &Bs[(p * 256 + tid) * 8]);
        }
        __syncthreads();
        bfrag af[4], bfr[4];
#pragma unroll
        for (int mi = 0; mi < 4; ++mi)
            af[mi] = *(const bfrag*)&As[((wm + mi * 16 + l16) * 4 + rsw) * 8];
#pragma unroll
        for (int ni = 0; ni < 4; ++ni)
            bfr[ni] = *(const bfrag*)&Bs[((wn + ni * 16 + l16) * 4 + rsw) * 8];
#pragma unroll
        for (int mi = 0; mi < 4; ++mi)
#pragma unroll
            for (int ni = 0; ni < 4; ++ni)
                acc[mi][ni] = __builtin_amdgcn_mfma_f32_16x16x32_bf16(af[mi], bfr[ni], acc[mi][ni], 0, 0, 0);
        aPtr += 32;
        bPtr += 32;
    }
#pragma unroll
    for (int mi = 0; mi < 4; ++mi)
#pragma unroll
        for (int ni = 0; ni < 4; ++ni)
#pragma unroll
            for (int r = 0; r < 4; ++r) {
                int row = bm + wm + mi * 16 + quad * 4 + r;
                int col = bn + wn + ni * 16 + l16;
                float v = acc[mi][ni][r];
                if constexpr (sizeof(OutT) == 2)
                    C[(size_t)row * ldc + col] = f2bf(v);
                else
                    C[(size_t)row * ldc + col] = v;
            }
}

// ---------------- RMSNorm + RoPE (q prescaled by softmax scale * log2e) ----------------
__global__ __launch_bounds__(256) void rmsrope(u16* __restrict__ qkv,
                                               const float* __restrict__ cosb,
                                               const float* __restrict__ sinb,
                                               const float* __restrict__ qw,
                                               const float* __restrict__ kw) {
    const float c1 = 0.08838834764831845f * LOG2E;
    int wave = threadIdx.x >> 6, lane = threadIdx.x & 63;
    int pi = blockIdx.x * 4 + wave;
    int m = pi / 20, hsel = pi % 20;
    int col0 = hsel < 16 ? hsel * 128 : 2048 + (hsel - 16) * 128;
    const float* w = hsel < 16 ? qw : kw;
    float sc = hsel < 16 ? c1 : 1.0f;
    int s = m & 2047;
    u16* p = qkv + (size_t)m * 3072 + col0;
    float x1 = bf2f(p[lane]), x2 = bf2f(p[lane + 64]);
    float ss = x1 * x1 + x2 * x2;
#pragma unroll
    for (int off = 32; off; off >>= 1) ss += __shfl_xor(ss, off, 64);
    float inv = rsqrtf(ss * (1.0f / 128.0f) + 1e-6f);
    float y1 = x1 * inv * w[lane], y2 = x2 * inv * w[lane + 64];
    const float* cp = cosb + (size_t)s * 128;
    const float* sp = sinb + (size_t)s * 128;
    float o1 = y1 * cp[lane] - y2 * sp[lane];
    float o2 = y2 * cp[lane + 64] + y1 * sp[lane + 64];
    p[lane] = f2bf(o1 * sc);
    p[lane + 64] = f2bf(o2 * sc);
}

// ---------------- V transpose ----------------
__global__ __launch_bounds__(256) void transpose_v(const u16* __restrict__ qkv,
                                                   u16* __restrict__ vT) {
    __shared__ u16 t[32][33];
    int bh = blockIdx.z, b = bh >> 2, kvh = bh & 3;
    int s0 = blockIdx.y * 32, d0 = blockIdx.x * 32;
    int tx = threadIdx.x, ty = threadIdx.y;
    const u16* src = qkv + (size_t)(b * 2048) * 3072 + 2560 + kvh * 128;
#pragma unroll
    for (int i = 0; i < 32; i += 8)
        t[ty + i][tx] = src[(size_t)(s0 + ty + i) * 3072 + d0 + tx];
    __syncthreads();
    u16* dst = vT + (size_t)bh * 128 * 2048;
#pragma unroll
    for (int i = 0; i < 32; i += 8)
        dst[(size_t)(d0 + ty + i) * 2048 + s0 + tx] = t[tx][ty + i];
}

// ---------------- causal flash attention (R3 structure + no-max softmax) ----------------
// grid (32 bh, 16 pairs), block 256 (4 waves). Block handles q-tiles {p, 31-p} of 64 rows:
// exactly 33 KV-tile (64-wide) iterations per block -> uniform work, all 512 blocks
// co-resident, no dispatch tail (this exact structure measured 103 us in R3).
// Delta vs R3: q pre-scaled by scale*log2e in rmsrope; softmax has NO running max
// (p = exp2(min(s,60)); max cancels in O/l) -> removes 2 shuffles + alpha-rescale of
// 32 accum registers per iteration (R3 was VALU-bound: 46% VALUBusy vs 21% MfmaUtil).
__global__ __launch_bounds__(256) void attn_kernel(const u16* __restrict__ qkv,
                                                   const u16* __restrict__ vT,
                                                   u16* __restrict__ out) {
    __shared__ u16 Ks[64 * 128];    // [kv][16B-chunk ^ (kv&15)]
    __shared__ u16 VsT[128 * 64];   // [d][16B-chunk ^ (d&7)]
    const int tid = threadIdx.x, wave = tid >> 6, lane = tid & 63;
    const int quad = lane >> 4, l16 = lane & 15;
    const int bh = blockIdx.x, b = bh >> 4, h = bh & 15, kvh = h >> 2;
    const int pair = blockIdx.y;
    const size_t rowBase = (size_t)b * 2048;
    const int kcol0 = 2048 + kvh * 128;
    const u16* vTbase = vT + (size_t)(b * 4 + kvh) * 128 * 2048;

#pragma unroll 1
    for (int ph = 0; ph < 2; ++ph) {
        const int qt = ph == 0 ? pair : 31 - pair;
        const int qrow = qt * 64 + wave * 16 + l16;  // this lane's q row

        // Q B-frags (K=32): lane n=l16 holds d = ks*32 + quad*8 + j, contiguous 16B
        const u16* qp = qkv + (rowBase + qrow) * 3072 + h * 128 + quad * 8;
        bfrag qf[4];
#pragma unroll
        for (int ks = 0; ks < 4; ++ks) qf[ks] = *(const bfrag*)(qp + ks * 32);

        f32x4 o[8] = {};  // O^T: 8 d-tiles x 1 q-tile, C-layout (row=d, col=q=l16)
        float lrun = 0.f;

        for (int kt = 0; kt <= qt; ++kt) {
            const int kv0 = kt * 64;
            __syncthreads();
#pragma unroll
            for (int i = 0; i < 4; ++i) {  // Ks: 64 rows x 16 chunks
                int c = i * 256 + tid, kv = c >> 4, cp2 = c & 15;
                gl_lds16(qkv + (rowBase + kv0 + kv) * 3072 + kcol0 + (cp2 ^ (kv & 15)) * 8,
                         &Ks[c * 8]);
            }
#pragma unroll
            for (int i = 0; i < 4; ++i) {  // VsT: 128 rows x 8 chunks
                int c = i * 256 + tid, d = c >> 3, cp2 = c & 7;
                gl_lds16(vTbase + (size_t)d * 2048 + kv0 + (cp2 ^ (d & 7)) * 8, &VsT[c * 8]);
            }
            __syncthreads();

            // S^T = K * Q^T : 4 kv-subtiles (m) x 1 q-subtile (scores already exp2-domain)
            f32x4 sa[4] = {};
#pragma unroll
            for (int ks = 0; ks < 4; ++ks)
#pragma unroll
                for (int m = 0; m < 4; ++m) {
                    bfrag kf = *(const bfrag*)&Ks[((m * 16 + l16) * 16 + ((ks * 4 + quad) ^ l16)) * 8];
                    sa[m] = __builtin_amdgcn_mfma_f32_16x16x32_bf16(kf, qf[ks], sa[m], 0, 0, 0);
                }

            // no-max softmax: p = exp2(min(s,60)); masked lanes -> 0 via -3e38
            if (kv0 + 63 > qt * 64 + wave * 16) {  // only the diagonal tile needs masking
#pragma unroll
                for (int m = 0; m < 4; ++m)
#pragma unroll
                    for (int r = 0; r < 4; ++r)
                        if (kv0 + m * 16 + quad * 4 + r > qrow) sa[m][r] = -3e38f;
            }
            float rs = 0.f;
#pragma unroll
            for (int m = 0; m < 4; ++m)
#pragma unroll
                for (int r = 0; r < 4; ++r) {
                    float pe = exp2f(fminf(sa[m][r], 60.f));
                    sa[m][r] = pe;
                    rs += pe;
                }
            rs += __shfl_xor(rs, 16, 64);
            rs += __shfl_xor(rs, 32, 64);
            lrun += rs;

            // O^T += V^T * P^T  (K=16 MFMA; P^T C-layout IS the B-layout)
            sh4 pf[4];
#pragma unroll
            for (int m = 0; m < 4; ++m) pf[m] = pack4(sa[m]);
#pragma unroll
            for (int k2 = 0; k2 < 4; ++k2) {
#pragma unroll
                for (int dt = 0; dt < 8; ++dt) {
                    int d = dt * 16 + l16;
                    int ch = k2 * 2 + (quad >> 1);
                    sh4 vf = *(const sh4*)&VsT[(d * 8 + (ch ^ (l16 & 7))) * 8 + (quad & 1) * 4];
                    o[dt] = pv_mfma(vf, pf[k2], o[dt]);
                }
            }
        }

        // epilogue: normalize, pack 4 bf16 (consecutive d), store 8B per (lane, dtile)
        float inv = 1.0f / lrun;
        size_t orow = (rowBase + qrow) * 2048 + h * 128 + quad * 4;
#pragma unroll
        for (int dt = 0; dt < 8; ++dt) {
            uint2 pk;
            pk.x = (unsigned)f2bf(o[dt][0] * inv) | ((unsigned)f2bf(o[dt][1] * inv) << 16);
            pk.y = (unsigned)f2bf(o[dt][2] * inv) | ((unsigned)f2bf(o[dt][3] * inv) << 16);
            *(uint2*)(out + orow + dt * 16) = pk;
        }
    }
}

extern "C" void kernel_launch(void* const* d_in, const int* in_sizes, int n_in,
                              void* d_out, int out_size, void* d_ws, size_t ws_size,
                              hipStream_t stream) {
    const float* hs   = (const float*)d_in[0];
    const float* cosb = (const float*)d_in[1];
    const float* sinb = (const float*)d_in[2];
    const float* Wq = (const float*)d_in[4];
    const float* Wk = (const float*)d_in[5];
    const float* Wv = (const float*)d_in[6];
    const float* Wo = (const float*)d_in[7];
    const float* qw = (const float*)d_in[8];
    const float* kw = (const float*)d_in[9];
    float* out = (float*)d_out;

    char* ws = (char*)d_ws;
    u16* hsb   = (u16*)(ws + 0);          // 16 MB: hs bf16; later reused as attn-out bf16
    u16* wqkvT = (u16*)(ws + 16777216);   // 12 MB
    u16* woT   = (u16*)(ws + 29360128);   // 8 MB
    u16* qkv   = (u16*)(ws + 37748736);   // 24 MB
    u16* vT    = (u16*)(ws + 62914560);   // 4 MB

    dim3 tb(32, 8);
    cvt_f32_bf16<<<8192, 256, 0, stream>>>(hs, hsb, 2097152);
    transpose_cvt<<<dim3(64, 64), tb, 0, stream>>>(Wq, wqkvT, 2048, 2048);
    transpose_cvt<<<dim3(16, 64), tb, 0, stream>>>(Wk, wqkvT + (size_t)2048 * 2048, 2048, 512);
    transpose_cvt<<<dim3(16, 64), tb, 0, stream>>>(Wv, wqkvT + (size_t)2560 * 2048, 2048, 512);
    transpose_cvt<<<dim3(64, 64), tb, 0, stream>>>(Wo, woT, 2048, 2048);

    gemm_bt<u16><<<dim3(32, 24), 256, 0, stream>>>(hsb, wqkvT, qkv, 2048, 3072);

    rmsrope<<<20480, 256, 0, stream>>>(qkv, cosb, sinb, qw, kw);
    transpose_v<<<dim3(4, 64, 8), tb, 0, stream>>>(qkv, vT);

    attn_kernel<<<dim3(32, 16), 256, 0, stream>>>(qkv, vT, hsb);

    gemm_bt<float><<<dim3(32, 16), 256, 0, stream>>>(hsb, woT, out, 2048, 2048);
}